// Round 10
// baseline (149.945 us; speedup 1.0000x reference)
//
#include <hip/hip_runtime.h>
#include <math.h>

#define D_   512
#define H_   4
#define KC   128
#define T_   1024
#define B_   4
#define NEG_ -10000.0f

typedef short bf16x8 __attribute__((ext_vector_type(8)));
typedef float f32x4  __attribute__((ext_vector_type(4)));

__device__ __forceinline__ ushort f2b_rne(float x) {
    unsigned u = __float_as_uint(x);
    u += 0x7fffu + ((u >> 16) & 1u);
    return (ushort)(u >> 16);
}

__device__ __forceinline__ uint4 pack8(const float4 a, const float4 b) {
    uint4 r;
    r.x = (unsigned)f2b_rne(a.x) | ((unsigned)f2b_rne(a.y) << 16);
    r.y = (unsigned)f2b_rne(a.z) | ((unsigned)f2b_rne(a.w) << 16);
    r.z = (unsigned)f2b_rne(b.x) | ((unsigned)f2b_rne(b.y) << 16);
    r.w = (unsigned)f2b_rne(b.z) | ((unsigned)f2b_rne(b.w) << 16);
    return r;
}

// 16-lane DPP reductions (quad_perm 1032, quad_perm 2301, row_half_mirror,
// row_mirror). ~1cy/step vs ~40cy ds_swizzle.
__device__ __forceinline__ float dpp16_max(float v) {
    v = fmaxf(v, __int_as_float(__builtin_amdgcn_mov_dpp(__float_as_int(v), 0xB1, 0xf, 0xf, true)));
    v = fmaxf(v, __int_as_float(__builtin_amdgcn_mov_dpp(__float_as_int(v), 0x4E, 0xf, 0xf, true)));
    v = fmaxf(v, __int_as_float(__builtin_amdgcn_mov_dpp(__float_as_int(v), 0x141, 0xf, 0xf, true)));
    v = fmaxf(v, __int_as_float(__builtin_amdgcn_mov_dpp(__float_as_int(v), 0x140, 0xf, 0xf, true)));
    return v;
}
__device__ __forceinline__ float dpp16_sum(float v) {
    v += __int_as_float(__builtin_amdgcn_mov_dpp(__float_as_int(v), 0xB1, 0xf, 0xf, true));
    v += __int_as_float(__builtin_amdgcn_mov_dpp(__float_as_int(v), 0x4E, 0xf, 0xf, true));
    v += __int_as_float(__builtin_amdgcn_mov_dpp(__float_as_int(v), 0x141, 0xf, 0xf, true));
    v += __int_as_float(__builtin_amdgcn_mov_dpp(__float_as_int(v), 0x140, 0xf, 0xf, true));
    return v;
}

// ---------------------------------------------------------------------------
// bf16 MFMA GEMM, fp32 inputs with INLINE conversion (replaces cvt_all pass).
// C[128x64 tile] = A * W^T + bias. Reg-staged: load fp32, f2b_rne pack,
// ds_write_b128 with write-side XOR swizzle (same involution the verified
// fragment reads expect). Same math as cvt_all + verified R2 gemm_tile ->
// bit-identical results.
//  mode 1: bf16 head-split [B,H,T,KC]
//  mode 2: bf16 head-split TRANSPOSED [B,H,KC,T]  (for V)
// ---------------------------------------------------------------------------
__device__ __forceinline__ void gemm_tile_f32(const float* __restrict__ A,
                                              const float* __restrict__ W,
                                              const float* __restrict__ bias,
                                              void* __restrict__ Cout, int mode,
                                              int m0, int n0)
{
    __shared__ __align__(16) ushort As[128 * 64];   // 16 KB
    __shared__ __align__(16) ushort Bs[64 * 64];    //  8 KB

    const int tid  = threadIdx.x;
    const int lane = tid & 63;
    const int wid  = tid >> 6;
    const int wm   = (wid >> 1) * 64;
    const int wn   = (wid & 1) * 32;
    const int frow = lane & 15;
    const int fq   = lane >> 4;

    f32x4 acc[4][2] = {};

    for (int k0 = 0; k0 < D_; k0 += 64) {
        __syncthreads();
        float4 fa[4][2], fw[2][2];
#pragma unroll
        for (int s = 0; s < 4; s++) {
            const int p = s * 256 + tid;
            const int r = p >> 3, cc = p & 7;
            const float4* pa = (const float4*)(A + (size_t)(m0 + r) * D_ + k0 + cc * 8);
            fa[s][0] = pa[0]; fa[s][1] = pa[1];
        }
#pragma unroll
        for (int s = 0; s < 2; s++) {
            const int p = s * 256 + tid;
            const int r = p >> 3, cc = p & 7;
            const float4* pw = (const float4*)(W + (size_t)(n0 + r) * D_ + k0 + cc * 8);
            fw[s][0] = pw[0]; fw[s][1] = pw[1];
        }
#pragma unroll
        for (int s = 0; s < 4; s++) {
            const int p = s * 256 + tid;
            const int r = p >> 3, cc = p & 7;
            *(uint4*)(As + r * 64 + ((cc ^ (r & 7)) * 8)) = pack8(fa[s][0], fa[s][1]);
        }
#pragma unroll
        for (int s = 0; s < 2; s++) {
            const int p = s * 256 + tid;
            const int r = p >> 3, cc = p & 7;
            *(uint4*)(Bs + r * 64 + ((cc ^ (r & 7)) * 8)) = pack8(fw[s][0], fw[s][1]);
        }
        __syncthreads();

#pragma unroll
        for (int kk = 0; kk < 2; kk++) {
            bf16x8 af[4], bf[2];
#pragma unroll
            for (int mt = 0; mt < 4; mt++) {
                const int r = wm + mt * 16 + frow;
                af[mt] = *(const bf16x8*)(As + r * 64 + (((kk * 4 + fq) ^ (r & 7)) * 8));
            }
#pragma unroll
            for (int nt = 0; nt < 2; nt++) {
                const int r = wn + nt * 16 + frow;
                bf[nt] = *(const bf16x8*)(Bs + r * 64 + (((kk * 4 + fq) ^ (r & 7)) * 8));
            }
#pragma unroll
            for (int mt = 0; mt < 4; mt++)
#pragma unroll
                for (int nt = 0; nt < 2; nt++)
                    acc[mt][nt] = __builtin_amdgcn_mfma_f32_16x16x32_bf16(
                        af[mt], bf[nt], acc[mt][nt], 0, 0, 0);
        }
    }

#pragma unroll
    for (int mt = 0; mt < 4; mt++)
#pragma unroll
        for (int nt = 0; nt < 2; nt++) {
            const int n = n0 + wn + nt * 16 + frow;
            const float bn = bias[n];
            const int mb = m0 + wm + mt * 16 + fq * 4;
            if (mode == 2) {
                const int b = mb >> 10, t0 = mb & (T_ - 1);
                const int h = n >> 7, kc = n & (KC - 1);
                ushort4 pk;
                pk.x = f2b_rne(acc[mt][nt][0] + bn);
                pk.y = f2b_rne(acc[mt][nt][1] + bn);
                pk.z = f2b_rne(acc[mt][nt][2] + bn);
                pk.w = f2b_rne(acc[mt][nt][3] + bn);
                *(ushort4*)((ushort*)Cout +
                    ((size_t)((b * H_ + h) * KC + kc)) * T_ + t0) = pk;
            } else {
#pragma unroll
                for (int r = 0; r < 4; r++) {
                    const int m = mb + r;
                    const float val = acc[mt][nt][r] + bn;
                    const int b = m >> 10, t = m & (T_ - 1);
                    const int h = n >> 7, kc = n & (KC - 1);
                    ((ushort*)Cout)[((size_t)((b * H_ + h) * T_ + t)) * KC + kc] =
                        f2b_rne(val);
                }
            }
        }
}

__global__ __launch_bounds__(256) void gemm_qkv(const float* __restrict__ x,
                                                const float* __restrict__ c,
                                                const float* __restrict__ Wq,
                                                const float* __restrict__ Wk,
                                                const float* __restrict__ Wv,
                                                const float* __restrict__ bq,
                                                const float* __restrict__ bk,
                                                const float* __restrict__ bv,
                                                ushort* qb, ushort* kb, ushort* vtb)
{
    const int m0 = (blockIdx.x >> 3) * 128;
    const int n0 = (blockIdx.x & 7) * 64;
    const int sub = blockIdx.y;
    const float* A; const float* W; const float* bi; void* C; int mode;
    if (sub == 0)      { A = x; W = Wq; bi = bq; C = qb;  mode = 1; }
    else if (sub == 1) { A = c; W = Wk; bi = bk; C = kb;  mode = 1; }
    else               { A = c; W = Wv; bi = bv; C = vtb; mode = 2; }
    gemm_tile_f32(A, W, bi, C, mode, m0, n0);
}

// ---------------------------------------------------------------------------
// Output projection: A = ab (bf16, via verified global_load_lds async path),
// W = Wo fp32 inline-converted (reg-staged; overlaps A's async staging).
// ---------------------------------------------------------------------------
__global__ __launch_bounds__(256) void gemm_o(const ushort* __restrict__ A,
                                              const float* __restrict__ W,
                                              const float* __restrict__ bias,
                                              float* __restrict__ Cout)
{
    __shared__ __align__(16) ushort As[128 * 64];   // 16 KB
    __shared__ __align__(16) ushort Bs[64 * 64];    //  8 KB

    const int tid  = threadIdx.x;
    const int m0 = (blockIdx.x >> 3) * 128;
    const int n0 = (blockIdx.x & 7) * 64;
    const int lane = tid & 63;
    const int wid  = tid >> 6;
    const int wm   = (wid >> 1) * 64;
    const int wn   = (wid & 1) * 32;
    const int frow = lane & 15;
    const int fq   = lane >> 4;

    f32x4 acc[4][2] = {};

    for (int k0 = 0; k0 < D_; k0 += 64) {
        __syncthreads();
        // A: async direct-to-LDS (inverse-swizzled source, verified R2)
#pragma unroll
        for (int s = 0; s < 4; s++) {
            const int p = s * 256 + tid;
            const int r = p >> 3;
            const int cc = (p & 7) ^ (r & 7);
            __builtin_amdgcn_global_load_lds(
                (const __attribute__((address_space(1))) void*)(A + (size_t)(m0 + r) * D_ + k0 + cc * 8),
                (__attribute__((address_space(3))) void*)(As + p * 8), 16, 0, 0);
        }
        // W: fp32 reg-staged inline convert (latency overlaps A's async)
        float4 fw[2][2];
#pragma unroll
        for (int s = 0; s < 2; s++) {
            const int p = s * 256 + tid;
            const int r = p >> 3, cc = p & 7;
            const float4* pw = (const float4*)(W + (size_t)(n0 + r) * D_ + k0 + cc * 8);
            fw[s][0] = pw[0]; fw[s][1] = pw[1];
        }
#pragma unroll
        for (int s = 0; s < 2; s++) {
            const int p = s * 256 + tid;
            const int r = p >> 3, cc = p & 7;
            *(uint4*)(Bs + r * 64 + ((cc ^ (r & 7)) * 8)) = pack8(fw[s][0], fw[s][1]);
        }
        __syncthreads();

#pragma unroll
        for (int kk = 0; kk < 2; kk++) {
            bf16x8 af[4], bf[2];
#pragma unroll
            for (int mt = 0; mt < 4; mt++) {
                const int r = wm + mt * 16 + frow;
                af[mt] = *(const bf16x8*)(As + r * 64 + (((kk * 4 + fq) ^ (r & 7)) * 8));
            }
#pragma unroll
            for (int nt = 0; nt < 2; nt++) {
                const int r = wn + nt * 16 + frow;
                bf[nt] = *(const bf16x8*)(Bs + r * 64 + (((kk * 4 + fq) ^ (r & 7)) * 8));
            }
#pragma unroll
            for (int mt = 0; mt < 4; mt++)
#pragma unroll
                for (int nt = 0; nt < 2; nt++)
                    acc[mt][nt] = __builtin_amdgcn_mfma_f32_16x16x32_bf16(
                        af[mt], bf[nt], acc[mt][nt], 0, 0, 0);
        }
    }

#pragma unroll
    for (int mt = 0; mt < 4; mt++)
#pragma unroll
        for (int nt = 0; nt < 2; nt++) {
            const int n = n0 + wn + nt * 16 + frow;
            const float bn = bias[n];
            const int mb = m0 + wm + mt * 16 + fq * 4;
#pragma unroll
            for (int r = 0; r < 4; r++)
                Cout[(size_t)(mb + r) * D_ + n] = acc[mt][nt][r] + bn;
        }
}

// ---------------------------------------------------------------------------
// MFMA flash attention v9 (byte-identical to R9-verified source).
// 256 blocks x 1024 thr = 16 waves = 4 groups x 4; XCD swizzle; K/V double-
// buffered global_load_lds staging; Ps wave-private; one barrier/iter.
// ---------------------------------------------------------------------------
__global__ __launch_bounds__(1024, 4) void attn_mfma(const ushort* __restrict__ qg,
                                                 const ushort* __restrict__ kg,
                                                 const ushort* __restrict__ vtg,
                                                 const float* __restrict__ mask,
                                                 const float* __restrict__ relk,
                                                 const float* __restrict__ relv,
                                                 ushort* __restrict__ outp)
{
    const int lin = blockIdx.x;
    const int bh  = ((lin & 7) << 1) | ((lin >> 3) & 1);  // XCD-locality swizzle
    const int i0  = (lin >> 4) * 64;
    const int b   = bh >> 2;
    const int h   = bh & 3;
    const int tid  = threadIdx.x;
    const int lane = tid & 63;
    const int wid  = tid >> 6;        // 0..15
    const int grp  = wid >> 2;        // wave group 0..3
    const int tgid = tid & 255;       // thread id within group
    const int c_   = lane & 15;
    const int quad = lane >> 4;
    const int c7   = c_ & 7;
    const int row0 = 16 * (wid & 3);

    // pool: [0,64K) K{grp,dbuf} 8K each; [64K,128K) V{grp,dbuf}; [128K,144K) Ps{grp}
    __shared__ __align__(16) char pool[147456];
    __shared__ float rlog[64][9];
    __shared__ float lg[257];
    __shared__ float mls[6][64];      // m1,l1,m2,l2,m3,l3

    ushort* Ps   = (ushort*)(pool + 131072 + grp * 4096);
    ushort* Krel = (ushort*)(pool + 131072);           // prologue-only overlay

    const float scale = 0.08838834764831845f;  // 1/sqrt(128)

    // ---- Q fragments straight from global: wave's own 16 rows ----
    bf16x8 aq[4];
#pragma unroll
    for (int ks = 0; ks < 4; ks++)
        aq[ks] = *(const bf16x8*)(qg +
            ((size_t)(bh * T_ + i0 + row0 + c_) * KC + ks * 32 + quad * 8));

    // ---- row mask in registers (this wave's 16 rows, per r4) ----
    float rm4[4];
#pragma unroll
    for (int r4 = 0; r4 < 4; r4++)
        rm4[r4] = mask[b * T_ + i0 + row0 + quad * 4 + r4];

    // ---- one-time tables (Krel overlays Ps region; Ps unused until loop) ----
    for (int e = tid; e < 1152; e += 1024) {
        const int d = e >> 7, kk = e & 127;
        Krel[d * 128 + (((kk >> 3) ^ (d & 7)) * 8) + (kk & 7)] = f2b_rne(relk[e]);
    }
    for (int e = tid; e < 257; e += 1024) lg[e] = log1pf((float)e);

    const int cstart = (i0 - 256 > 0) ? (i0 - 256) : 0;
    const int cend   = (i0 + 64 + 256 < T_) ? (i0 + 64 + 256) : T_;
    const int ntl    = (cend - cstart) >> 5;   // 32-col tiles, in [10,18]
    const int ntt    = (ntl + 3) >> 2;         // lockstep iterations per group

    // ---- async K/V 32-col tile staging via global_load_lds (zero VGPRs) ----
    auto stage = [&](int j0, int dbuf) {
        ushort* Kd = (ushort*)(pool + grp * 16384 + dbuf * 8192);
        ushort* Vd = (ushort*)(pool + 65536 + grp * 16384 + dbuf * 8192);
#pragma unroll
        for (int s = 0; s < 2; s++) {
            const int e = s * 256 + tgid;
            const int r = e >> 4;
            const int cc = (e & 15) ^ (r & 7);
            __builtin_amdgcn_global_load_lds(
                (const __attribute__((address_space(1))) void*)(kg + (size_t)(bh * T_ + j0 + r) * KC + cc * 8),
                (__attribute__((address_space(3))) void*)(Kd + e * 8), 16, 0, 0);
        }
#pragma unroll
        for (int s = 0; s < 2; s++) {
            const int e = s * 256 + tgid;
            const int ch = e >> 2;
            const int kv = (e & 3) ^ (ch & 3);
            __builtin_amdgcn_global_load_lds(
                (const __attribute__((address_space(1))) void*)(vtg + (size_t)(bh * KC + ch) * T_ + j0 + kv * 8),
                (__attribute__((address_space(3))) void*)(Vd + e * 8), 16, 0, 0);
        }
    };

    // prologue: stage own group's first tile into buf 0 (async)
    stage(cstart + grp * 32, 0);

    __syncthreads();   // Krel visible (also drains prologue staging)

    // ---- rel-k logits via MFMA (group 0 only) ----
    if (grp == 0) {
        f32x4 racc = {};
#pragma unroll
        for (int ks = 0; ks < 4; ks++) {
            const int sw = ((ks * 4 + quad) ^ c7) * 8;
            const bf16x8 bk = *(const bf16x8*)(Krel + c_ * 128 + sw);
            racc = __builtin_amdgcn_mfma_f32_16x16x32_bf16(aq[ks], bk, racc, 0, 0, 0);
        }
        if (c_ < 9) {
#pragma unroll
            for (int r4 = 0; r4 < 4; r4++)
                rlog[row0 + quad * 4 + r4][c_] = racc[r4] * scale;
        }
    }
    __syncthreads();   // rlog visible; Ps region free for softmax

    float m_run[4], l_run[4], pdacc[4];
    int pdw[4];
    f32x4 acco[8] = {};
#pragma unroll
    for (int r4 = 0; r4 < 4; r4++) {
        m_run[r4] = -1e30f; l_run[r4] = 0.f; pdacc[r4] = 0.f; pdw[r4] = -1;
    }

    int cur = 0;
    for (int tt = 0; tt < ntt; tt++) {
        const int t = 4 * tt + grp;
        const int tn = t + 4;
        if (tn < ntl) stage(cstart + tn * 32, cur ^ 1);  // async into spare buf

        if (t < ntl) {
            const int j0 = cstart + t * 32;
            ushort* Ks = (ushort*)(pool + grp * 16384 + cur * 8192);
            ushort* Vt = (ushort*)(pool + 65536 + grp * 16384 + cur * 8192);

            // ---- S = Q . K^T : 8 MFMAs per wave ----
            f32x4 accs[2] = {};
            __builtin_amdgcn_s_setprio(1);
#pragma unroll
            for (int ks = 0; ks < 4; ks++) {
                const int sw = ((ks * 4 + quad) ^ c7) * 8;
#pragma unroll
                for (int ct = 0; ct < 2; ct++) {
                    const bf16x8 bk = *(const bf16x8*)(Ks + (ct * 16 + c_) * 128 + sw);
                    accs[ct] = __builtin_amdgcn_mfma_f32_16x16x32_bf16(aq[ks], bk, accs[ct], 0, 0, 0);
                }
            }
            __builtin_amdgcn_s_setprio(0);

            // ---- column mask per-lane (L2 hit) ----
            float mskv[2];
#pragma unroll
            for (int ct = 0; ct < 2; ct++) mskv[ct] = mask[b * T_ + j0 + ct * 16 + c_];

            // ---- online softmax on C-layout fragments ----
            float alpha4[4];
#pragma unroll
            for (int r4 = 0; r4 < 4; r4++) {
                const int row = row0 + quad * 4 + r4;
                const float rm = rm4[r4];
                const int dj = j0 - i0 + c_ - row;  // d at ct=0
                float sv[2];
                float mt = -3e38f;
#pragma unroll
                for (int ct = 0; ct < 2; ct++) {
                    const int d = dj + ct * 16;
                    const unsigned ad = (unsigned)((d < 0) ? -d : d);
                    float s;
                    if (rm != 0.f && mskv[ct] != 0.f && ad <= 256u) {
                        s = accs[ct][r4] * scale - lg[ad];
                        const unsigned dw = (unsigned)(d + 4);
                        if (dw <= 8u) s += rlog[row][dw];
                    } else {
                        s = NEG_;
                    }
                    sv[ct] = s;
                    mt = fmaxf(mt, s);
                }
                mt = dpp16_max(mt);
                const float mnew = fmaxf(m_run[r4], mt);
                const float al = __expf(m_run[r4] - mnew);
                alpha4[r4] = al;
                m_run[r4] = mnew;
                pdacc[r4] *= al;

                const int row3 = row & 3;
                float lt = 0.f;
#pragma unroll
                for (int ct = 0; ct < 2; ct++) {
                    const float p = __expf(sv[ct] - mnew);
                    sv[ct] = p;
                    lt += p;
                    Ps[row * 32 + (((2 * ct + (c_ >> 3)) ^ row3) * 8) + c7] = f2b_rne(p);
                }
                lt = dpp16_sum(lt);
                l_run[r4] = l_run[r4] * al + lt;

                // pdiag window: each lane hits at most one (row,dw) slot ever
#pragma unroll
                for (int ct = 0; ct < 2; ct++) {
                    const int d = dj + ct * 16;
                    const unsigned dw = (unsigned)(d + 4);
                    if (dw <= 8u) { pdacc[r4] += sv[ct]; pdw[r4] = (int)dw; }
                }
            }

            // ---- O *= alpha ----
#pragma unroll
            for (int nt = 0; nt < 8; nt++)
#pragma unroll
                for (int r4 = 0; r4 < 4; r4++) acco[nt][r4] *= alpha4[r4];

            // ---- PV: 8 MFMAs; Ps wave-private (in-wave lgkm ordering) ----
            const int prow = row0 + c_;
            const bf16x8 ap = *(const bf16x8*)(Ps + prow * 32 + ((quad ^ (prow & 3)) * 8));
            __builtin_amdgcn_s_setprio(1);
#pragma unroll
            for (int nt = 0; nt < 8; nt++) {
                const int ch = nt * 16 + c_;
                const bf16x8 bv = *(const bf16x8*)(Vt + ch * 32 + ((quad ^ (ch & 3)) * 8));
                acco[nt] = __builtin_amdgcn_mfma_f32_16x16x32_bf16(ap, bv, acco[nt], 0, 0, 0);
            }
            __builtin_amdgcn_s_setprio(0);
        }

        // ONE barrier: vmcnt drain completes staging of buf^1; all reads of
        // buf[cur] done -> next iteration may stage into it.
        __syncthreads();
        cur ^= 1;
    }

    // ---- epilogue overlays on dead pool regions ----
    float* Ocomb  = (float*)pool;              // 3 x 32K at (grp-1)*32768
    float* relv_s = (float*)(pool + 98304);    // 4.5 KB (dead V region)
    float* pdiag4 = (float*)(pool + 104448);   // 4*64*9*4 = 9 KB (dead V region)

    // zero pdiag, stage relv, dump merge state (all regions disjoint)
    for (int e = tid; e < 2304; e += 1024) pdiag4[e] = 0.f;
    for (int e = tid; e < 1152; e += 1024) relv_s[e] = relv[e];
    if (grp != 0) {
        float* Oc = Ocomb + (grp - 1) * 8192;
        float* ms = mls[2 * (grp - 1)];
        float* ls = mls[2 * (grp - 1) + 1];
#pragma unroll
        for (int r4 = 0; r4 < 4; r4++) {
            const int row = row0 + quad * 4 + r4;
            if (c_ == 0) { ms[row] = m_run[r4]; ls[row] = l_run[r4]; }
#pragma unroll
            for (int nt = 0; nt < 8; nt++)
                Oc[row * 128 + nt * 16 + c_] = acco[nt][r4];
        }
    }
    __syncthreads();

    // dump register pdiag slots into zeroed table (disjoint (grp,row,dw))
#pragma unroll
    for (int r4 = 0; r4 < 4; r4++)
        if (pdw[r4] >= 0)
            pdiag4[(grp * 64 + row0 + quad * 4 + r4) * 9 + pdw[r4]] = pdacc[r4];
    __syncthreads();

    // ---- epilogue (group 0): 4-way combine, rel-v via pdiag, store ----
    if (grp == 0) {
#pragma unroll
        for (int r4 = 0; r4 < 4; r4++) {
            const int row = row0 + quad * 4 + r4;
            const int i = i0 + row;
            const float m0v = m_run[r4];
            const float m1v = mls[0][row], m2v = mls[2][row], m3v = mls[4][row];
            const float mn = fmaxf(fmaxf(m0v, m1v), fmaxf(m2v, m3v));
            const float a0 = __expf(m0v - mn);
            const float a1 = __expf(m1v - mn);
            const float a2 = __expf(m2v - mn);
            const float a3 = __expf(m3v - mn);
            const float l = l_run[r4] * a0 + mls[1][row] * a1 +
                            mls[3][row] * a2 + mls[5][row] * a3;
            const float invl = 1.f / l;
            float pd[9];
#pragma unroll
            for (int dd = 0; dd < 9; dd++) {
                const int j = i + dd - 4;
                pd[dd] = (j >= 0 && j < T_)
                    ? (pdiag4[(row) * 9 + dd] * a0 +
                       pdiag4[(64 + row) * 9 + dd] * a1 +
                       pdiag4[(128 + row) * 9 + dd] * a2 +
                       pdiag4[(192 + row) * 9 + dd] * a3) : 0.f;
            }
            ushort* ob = outp + ((size_t)(b * T_ + i) * H_ + h) * KC;
#pragma unroll
            for (int nt = 0; nt < 8; nt++) {
                const int col = nt * 16 + c_;
                float o = acco[nt][r4] * a0 +
                          Ocomb[row * 128 + col] * a1 +
                          Ocomb[8192 + row * 128 + col] * a2 +
                          Ocomb[16384 + row * 128 + col] * a3;
#pragma unroll
                for (int dd = 0; dd < 9; dd++) o += pd[dd] * relv_s[dd * 128 + col];
                ob[col] = f2b_rne(o * invl);
            }
        }
    }
}

// ---------------------------------------------------------------------------
extern "C" void kernel_launch(void* const* d_in, const int* in_sizes, int n_in,
                              void* d_out, int out_size, void* d_ws, size_t ws_size,
                              hipStream_t stream)
{
    const float* x    = (const float*)d_in[0];
    const float* c    = (const float*)d_in[1];
    const float* am   = (const float*)d_in[2];
    const float* Wq   = (const float*)d_in[3];
    const float* bq   = (const float*)d_in[4];
    const float* Wk   = (const float*)d_in[5];
    const float* bk   = (const float*)d_in[6];
    const float* Wv   = (const float*)d_in[7];
    const float* bv   = (const float*)d_in[8];
    const float* Wo   = (const float*)d_in[9];
    const float* bo   = (const float*)d_in[10];
    const float* relk = (const float*)d_in[11];
    const float* relv = (const float*)d_in[12];

    float* out = (float*)d_out;
    char* w8 = (char*)d_ws;
    ushort* qb  = (ushort*)(w8);
    ushort* kb  = (ushort*)(w8 + (4u << 20));
    ushort* vtb = (ushort*)(w8 + (8u << 20));   // [B,H,KC,T]
    ushort* ab  = (ushort*)(w8 + (12u << 20));

    gemm_qkv<<<dim3(256, 3), 256, 0, stream>>>(x, c, Wq, Wk, Wv,
                                               bq, bk, bv, qb, kb, vtb);

    attn_mfma<<<256, 1024, 0, stream>>>(qb, kb, vtb, am, relk, relv, ab);

    gemm_o<<<dim3(256, 1), 256, 0, stream>>>(ab, Wo, bo, out);
}

// Round 11
// 140.904 us; speedup vs baseline: 1.0642x; 1.0642x over previous
//
#include <hip/hip_runtime.h>
#include <math.h>

#define D_   512
#define H_   4
#define KC   128
#define T_   1024
#define B_   4
#define NEG_ -10000.0f

typedef short bf16x8 __attribute__((ext_vector_type(8)));
typedef float f32x4  __attribute__((ext_vector_type(4)));

__device__ __forceinline__ ushort f2b_rne(float x) {
    unsigned u = __float_as_uint(x);
    u += 0x7fffu + ((u >> 16) & 1u);
    return (ushort)(u >> 16);
}

// 16-lane DPP reductions (quad_perm 1032, quad_perm 2301, row_half_mirror,
// row_mirror). ~1cy/step vs ~40cy ds_swizzle.
__device__ __forceinline__ float dpp16_max(float v) {
    v = fmaxf(v, __int_as_float(__builtin_amdgcn_mov_dpp(__float_as_int(v), 0xB1, 0xf, 0xf, true)));
    v = fmaxf(v, __int_as_float(__builtin_amdgcn_mov_dpp(__float_as_int(v), 0x4E, 0xf, 0xf, true)));
    v = fmaxf(v, __int_as_float(__builtin_amdgcn_mov_dpp(__float_as_int(v), 0x141, 0xf, 0xf, true)));
    v = fmaxf(v, __int_as_float(__builtin_amdgcn_mov_dpp(__float_as_int(v), 0x140, 0xf, 0xf, true)));
    return v;
}
__device__ __forceinline__ float dpp16_sum(float v) {
    v += __int_as_float(__builtin_amdgcn_mov_dpp(__float_as_int(v), 0xB1, 0xf, 0xf, true));
    v += __int_as_float(__builtin_amdgcn_mov_dpp(__float_as_int(v), 0x4E, 0xf, 0xf, true));
    v += __int_as_float(__builtin_amdgcn_mov_dpp(__float_as_int(v), 0x141, 0xf, 0xf, true));
    v += __int_as_float(__builtin_amdgcn_mov_dpp(__float_as_int(v), 0x140, 0xf, 0xf, true));
    return v;
}

// ---------------------------------------------------------------------------
// fused fp32 -> bf16 converter for all 6 tensors (one launch)
// ---------------------------------------------------------------------------
__global__ __launch_bounds__(256) void cvt_all(const float* __restrict__ x,
                                               const float* __restrict__ c,
                                               const float* __restrict__ w0,
                                               const float* __restrict__ w1,
                                               const float* __restrict__ w2,
                                               const float* __restrict__ w3,
                                               ushort* xo, ushort* co,
                                               ushort* o0, ushort* o1,
                                               ushort* o2, ushort* o3)
{
    const int blk = blockIdx.x;
    const float* src; ushort* dst; int base;
    if (blk < 1024)      { src = x; dst = xo; base = blk; }
    else if (blk < 2048) { src = c; dst = co; base = blk - 1024; }
    else {
        const int w = (blk - 2048) >> 7;
        base = (blk - 2048) & 127;
        src = (w == 0) ? w0 : (w == 1) ? w1 : (w == 2) ? w2 : w3;
        dst = (w == 0) ? o0 : (w == 1) ? o1 : (w == 2) ? o2 : o3;
    }
    const int i = base * 256 + threadIdx.x;
    const float4 a = ((const float4*)src)[2 * i];
    const float4 b = ((const float4*)src)[2 * i + 1];
    uint4 r;
    r.x = (unsigned)f2b_rne(a.x) | ((unsigned)f2b_rne(a.y) << 16);
    r.y = (unsigned)f2b_rne(a.z) | ((unsigned)f2b_rne(a.w) << 16);
    r.z = (unsigned)f2b_rne(b.x) | ((unsigned)f2b_rne(b.y) << 16);
    r.w = (unsigned)f2b_rne(b.z) | ((unsigned)f2b_rne(b.w) << 16);
    ((uint4*)dst)[i] = r;
}

// ---------------------------------------------------------------------------
// bf16 MFMA GEMM core: C[128x64 tile] = A * W^T + bias   (verified in R2)
// ---------------------------------------------------------------------------
__device__ __forceinline__ void gemm_tile(const ushort* __restrict__ A,
                                          const ushort* __restrict__ W,
                                          const float* __restrict__ bias,
                                          void* __restrict__ Cout, int mode,
                                          int m0, int n0)
{
    __shared__ __align__(16) ushort As[128 * 64];   // 16 KB
    __shared__ __align__(16) ushort Bs[64 * 64];    //  8 KB

    const int tid  = threadIdx.x;
    const int lane = tid & 63;
    const int wid  = tid >> 6;
    const int wm   = (wid >> 1) * 64;
    const int wn   = (wid & 1) * 32;
    const int frow = lane & 15;
    const int fq   = lane >> 4;

    f32x4 acc[4][2] = {};

    for (int k0 = 0; k0 < D_; k0 += 64) {
        __syncthreads();
#pragma unroll
        for (int s = 0; s < 4; s++) {
            const int p = s * 256 + tid;
            const int r = p >> 3;
            const int cc = (p & 7) ^ (r & 7);
            __builtin_amdgcn_global_load_lds(
                (const __attribute__((address_space(1))) void*)(A + (size_t)(m0 + r) * D_ + k0 + cc * 8),
                (__attribute__((address_space(3))) void*)(As + p * 8), 16, 0, 0);
        }
#pragma unroll
        for (int s = 0; s < 2; s++) {
            const int p = s * 256 + tid;
            const int r = p >> 3;
            const int cc = (p & 7) ^ (r & 7);
            __builtin_amdgcn_global_load_lds(
                (const __attribute__((address_space(1))) void*)(W + (size_t)(n0 + r) * D_ + k0 + cc * 8),
                (__attribute__((address_space(3))) void*)(Bs + p * 8), 16, 0, 0);
        }
        __syncthreads();

#pragma unroll
        for (int kk = 0; kk < 2; kk++) {
            bf16x8 af[4], bf[2];
#pragma unroll
            for (int mt = 0; mt < 4; mt++) {
                const int r = wm + mt * 16 + frow;
                af[mt] = *(const bf16x8*)(As + r * 64 + (((kk * 4 + fq) ^ (r & 7)) * 8));
            }
#pragma unroll
            for (int nt = 0; nt < 2; nt++) {
                const int r = wn + nt * 16 + frow;
                bf[nt] = *(const bf16x8*)(Bs + r * 64 + (((kk * 4 + fq) ^ (r & 7)) * 8));
            }
#pragma unroll
            for (int mt = 0; mt < 4; mt++)
#pragma unroll
                for (int nt = 0; nt < 2; nt++)
                    acc[mt][nt] = __builtin_amdgcn_mfma_f32_16x16x32_bf16(
                        af[mt], bf[nt], acc[mt][nt], 0, 0, 0);
        }
    }

#pragma unroll
    for (int mt = 0; mt < 4; mt++)
#pragma unroll
        for (int nt = 0; nt < 2; nt++) {
            const int n = n0 + wn + nt * 16 + frow;
            const float bn = bias[n];
            const int mb = m0 + wm + mt * 16 + fq * 4;
            if (mode == 2) {
                const int b = mb >> 10, t0 = mb & (T_ - 1);
                const int h = n >> 7, kc = n & (KC - 1);
                ushort4 pk;
                pk.x = f2b_rne(acc[mt][nt][0] + bn);
                pk.y = f2b_rne(acc[mt][nt][1] + bn);
                pk.z = f2b_rne(acc[mt][nt][2] + bn);
                pk.w = f2b_rne(acc[mt][nt][3] + bn);
                *(ushort4*)((ushort*)Cout +
                    ((size_t)((b * H_ + h) * KC + kc)) * T_ + t0) = pk;
            } else {
#pragma unroll
                for (int r = 0; r < 4; r++) {
                    const int m = mb + r;
                    const float val = acc[mt][nt][r] + bn;
                    if (mode == 1) {
                        const int b = m >> 10, t = m & (T_ - 1);
                        const int h = n >> 7, kc = n & (KC - 1);
                        ((ushort*)Cout)[((size_t)((b * H_ + h) * T_ + t)) * KC + kc] =
                            f2b_rne(val);
                    } else {
                        ((float*)Cout)[(size_t)m * D_ + n] = val;
                    }
                }
            }
        }
}

__global__ __launch_bounds__(256) void gemm_qkv(const ushort* __restrict__ xb,
                                                const ushort* __restrict__ cb,
                                                const ushort* __restrict__ Wqb,
                                                const ushort* __restrict__ Wkb,
                                                const ushort* __restrict__ Wvb,
                                                const float* __restrict__ bq,
                                                const float* __restrict__ bk,
                                                const float* __restrict__ bv,
                                                ushort* qb, ushort* kb, ushort* vtb)
{
    const int m0 = (blockIdx.x >> 3) * 128;
    const int n0 = (blockIdx.x & 7) * 64;
    const int sub = blockIdx.y;
    const ushort* A; const ushort* W; const float* bi; void* C; int mode;
    if (sub == 0)      { A = xb; W = Wqb; bi = bq; C = qb;  mode = 1; }
    else if (sub == 1) { A = cb; W = Wkb; bi = bk; C = kb;  mode = 1; }
    else               { A = cb; W = Wvb; bi = bv; C = vtb; mode = 2; }
    gemm_tile(A, W, bi, C, mode, m0, n0);
}

__global__ __launch_bounds__(256) void gemm_o(const ushort* __restrict__ A,
                                              const ushort* __restrict__ W,
                                              const float* __restrict__ bias,
                                              float* __restrict__ C)
{
    gemm_tile(A, W, bias, C, 0, (blockIdx.x >> 3) * 128, (blockIdx.x & 7) * 64);
}

// ---------------------------------------------------------------------------
// MFMA flash attention v9. 256 blocks x 1024 thr = 16 waves = 4 groups x 4.
// 4 waves/SIMD and KVBLK=32. K/V staged per group into double-buffered LDS
// via global_load_lds (zero VGPR, async; verified R8). Slot s holds global
// chunk s^(row&mask) on BOTH stage and read sides (rule #21 involution).
// Ps wave-private; Q/mask/pdiag in regs; DPP reductions; one barrier/iter.
// Post-loop overlays on dead pool: Ocomb(3x32K), relv_s, pdiag4.
// ---------------------------------------------------------------------------
__global__ __launch_bounds__(1024, 4) void attn_mfma(const ushort* __restrict__ qg,
                                                 const ushort* __restrict__ kg,
                                                 const ushort* __restrict__ vtg,
                                                 const float* __restrict__ mask,
                                                 const float* __restrict__ relk,
                                                 const float* __restrict__ relv,
                                                 ushort* __restrict__ outp)
{
    const int lin = blockIdx.x;
    const int bh  = ((lin & 7) << 1) | ((lin >> 3) & 1);  // XCD-locality swizzle
    const int i0  = (lin >> 4) * 64;
    const int b   = bh >> 2;
    const int h   = bh & 3;
    const int tid  = threadIdx.x;
    const int lane = tid & 63;
    const int wid  = tid >> 6;        // 0..15
    const int grp  = wid >> 2;        // wave group 0..3
    const int tgid = tid & 255;       // thread id within group
    const int c_   = lane & 15;
    const int quad = lane >> 4;
    const int c7   = c_ & 7;
    const int row0 = 16 * (wid & 3);

    // pool: [0,64K) K{grp,dbuf} 8K each; [64K,128K) V{grp,dbuf}; [128K,144K) Ps{grp}
    __shared__ __align__(16) char pool[147456];
    __shared__ float rlog[64][9];
    __shared__ float lg[257];
    __shared__ float mls[6][64];      // m1,l1,m2,l2,m3,l3

    ushort* Ps   = (ushort*)(pool + 131072 + grp * 4096);
    ushort* Krel = (ushort*)(pool + 131072);           // prologue-only overlay

    const float scale = 0.08838834764831845f;  // 1/sqrt(128)

    // ---- Q fragments straight from global: wave's own 16 rows ----
    bf16x8 aq[4];
#pragma unroll
    for (int ks = 0; ks < 4; ks++)
        aq[ks] = *(const bf16x8*)(qg +
            ((size_t)(bh * T_ + i0 + row0 + c_) * KC + ks * 32 + quad * 8));

    // ---- row mask in registers (this wave's 16 rows, per r4) ----
    float rm4[4];
#pragma unroll
    for (int r4 = 0; r4 < 4; r4++)
        rm4[r4] = mask[b * T_ + i0 + row0 + quad * 4 + r4];

    // ---- one-time tables (Krel overlays Ps region; Ps unused until loop) ----
    for (int e = tid; e < 1152; e += 1024) {
        const int d = e >> 7, kk = e & 127;
        Krel[d * 128 + (((kk >> 3) ^ (d & 7)) * 8) + (kk & 7)] = f2b_rne(relk[e]);
    }
    for (int e = tid; e < 257; e += 1024) lg[e] = log1pf((float)e);

    const int cstart = (i0 - 256 > 0) ? (i0 - 256) : 0;
    const int cend   = (i0 + 64 + 256 < T_) ? (i0 + 64 + 256) : T_;
    const int ntl    = (cend - cstart) >> 5;   // 32-col tiles, in [10,18]
    const int ntt    = (ntl + 3) >> 2;         // lockstep iterations per group

    // ---- async K/V 32-col tile staging via global_load_lds (zero VGPRs) ----
    // K slot e: row r=e>>4 (0..31), slot c8=e&15 <- global chunk c8^(r&7)
    // V slot e: ch=e>>2 (0..127), slot k8=e&3  <- global chunk k8^(ch&3)
    auto stage = [&](int j0, int dbuf) {
        ushort* Kd = (ushort*)(pool + grp * 16384 + dbuf * 8192);
        ushort* Vd = (ushort*)(pool + 65536 + grp * 16384 + dbuf * 8192);
#pragma unroll
        for (int s = 0; s < 2; s++) {
            const int e = s * 256 + tgid;
            const int r = e >> 4;
            const int cc = (e & 15) ^ (r & 7);
            __builtin_amdgcn_global_load_lds(
                (const __attribute__((address_space(1))) void*)(kg + (size_t)(bh * T_ + j0 + r) * KC + cc * 8),
                (__attribute__((address_space(3))) void*)(Kd + e * 8), 16, 0, 0);
        }
#pragma unroll
        for (int s = 0; s < 2; s++) {
            const int e = s * 256 + tgid;
            const int ch = e >> 2;
            const int kv = (e & 3) ^ (ch & 3);
            __builtin_amdgcn_global_load_lds(
                (const __attribute__((address_space(1))) void*)(vtg + (size_t)(bh * KC + ch) * T_ + j0 + kv * 8),
                (__attribute__((address_space(3))) void*)(Vd + e * 8), 16, 0, 0);
        }
    };

    // prologue: stage own group's first tile into buf 0 (async)
    stage(cstart + grp * 32, 0);

    __syncthreads();   // Krel visible (also drains prologue staging)

    // ---- rel-k logits via MFMA (group 0 only) ----
    if (grp == 0) {
        f32x4 racc = {};
#pragma unroll
        for (int ks = 0; ks < 4; ks++) {
            const int sw = ((ks * 4 + quad) ^ c7) * 8;
            const bf16x8 bk = *(const bf16x8*)(Krel + c_ * 128 + sw);
            racc = __builtin_amdgcn_mfma_f32_16x16x32_bf16(aq[ks], bk, racc, 0, 0, 0);
        }
        if (c_ < 9) {
#pragma unroll
            for (int r4 = 0; r4 < 4; r4++)
                rlog[row0 + quad * 4 + r4][c_] = racc[r4] * scale;
        }
    }
    __syncthreads();   // rlog visible; Ps region free for softmax

    float m_run[4], l_run[4], pdacc[4];
    int pdw[4];
    f32x4 acco[8] = {};
#pragma unroll
    for (int r4 = 0; r4 < 4; r4++) {
        m_run[r4] = -1e30f; l_run[r4] = 0.f; pdacc[r4] = 0.f; pdw[r4] = -1;
    }

    int cur = 0;
    for (int tt = 0; tt < ntt; tt++) {
        const int t = 4 * tt + grp;
        const int tn = t + 4;
        if (tn < ntl) stage(cstart + tn * 32, cur ^ 1);  // async into spare buf

        if (t < ntl) {
            const int j0 = cstart + t * 32;
            ushort* Ks = (ushort*)(pool + grp * 16384 + cur * 8192);
            ushort* Vt = (ushort*)(pool + 65536 + grp * 16384 + cur * 8192);

            // ---- S = Q . K^T : 8 MFMAs per wave ----
            f32x4 accs[2] = {};
            __builtin_amdgcn_s_setprio(1);
#pragma unroll
            for (int ks = 0; ks < 4; ks++) {
                const int sw = ((ks * 4 + quad) ^ c7) * 8;
#pragma unroll
                for (int ct = 0; ct < 2; ct++) {
                    const bf16x8 bk = *(const bf16x8*)(Ks + (ct * 16 + c_) * 128 + sw);
                    accs[ct] = __builtin_amdgcn_mfma_f32_16x16x32_bf16(aq[ks], bk, accs[ct], 0, 0, 0);
                }
            }
            __builtin_amdgcn_s_setprio(0);

            // ---- column mask per-lane (L2 hit) ----
            float mskv[2];
#pragma unroll
            for (int ct = 0; ct < 2; ct++) mskv[ct] = mask[b * T_ + j0 + ct * 16 + c_];

            // ---- online softmax on C-layout fragments ----
            float alpha4[4];
#pragma unroll
            for (int r4 = 0; r4 < 4; r4++) {
                const int row = row0 + quad * 4 + r4;
                const float rm = rm4[r4];
                const int dj = j0 - i0 + c_ - row;  // d at ct=0
                float sv[2];
                float mt = -3e38f;
#pragma unroll
                for (int ct = 0; ct < 2; ct++) {
                    const int d = dj + ct * 16;
                    const unsigned ad = (unsigned)((d < 0) ? -d : d);
                    float s;
                    if (rm != 0.f && mskv[ct] != 0.f && ad <= 256u) {
                        s = accs[ct][r4] * scale - lg[ad];
                        const unsigned dw = (unsigned)(d + 4);
                        if (dw <= 8u) s += rlog[row][dw];
                    } else {
                        s = NEG_;
                    }
                    sv[ct] = s;
                    mt = fmaxf(mt, s);
                }
                mt = dpp16_max(mt);
                const float mnew = fmaxf(m_run[r4], mt);
                const float al = __expf(m_run[r4] - mnew);
                alpha4[r4] = al;
                m_run[r4] = mnew;
                pdacc[r4] *= al;

                const int row3 = row & 3;
                float lt = 0.f;
#pragma unroll
                for (int ct = 0; ct < 2; ct++) {
                    const float p = __expf(sv[ct] - mnew);
                    sv[ct] = p;
                    lt += p;
                    // col chunk = 2ct+(c_>>3) in [0,4); slot = chunk^(row&3)
                    Ps[row * 32 + (((2 * ct + (c_ >> 3)) ^ row3) * 8) + c7] = f2b_rne(p);
                }
                lt = dpp16_sum(lt);
                l_run[r4] = l_run[r4] * al + lt;

                // pdiag window: each lane hits at most one (row,dw) slot ever
#pragma unroll
                for (int ct = 0; ct < 2; ct++) {
                    const int d = dj + ct * 16;
                    const unsigned dw = (unsigned)(d + 4);
                    if (dw <= 8u) { pdacc[r4] += sv[ct]; pdw[r4] = (int)dw; }
                }
            }

            // ---- O *= alpha ----
#pragma unroll
            for (int nt = 0; nt < 8; nt++)
#pragma unroll
                for (int r4 = 0; r4 < 4; r4++) acco[nt][r4] *= alpha4[r4];

            // ---- PV: 8 MFMAs; Ps wave-private (in-wave lgkm ordering) ----
            // A-frag: lane (c_,quad) = P[row0+c_][quad*8..+7]; slot=quad^(row&3)
            const int prow = row0 + c_;
            const bf16x8 ap = *(const bf16x8*)(Ps + prow * 32 + ((quad ^ (prow & 3)) * 8));
            __builtin_amdgcn_s_setprio(1);
#pragma unroll
            for (int nt = 0; nt < 8; nt++) {
                const int ch = nt * 16 + c_;
                const bf16x8 bv = *(const bf16x8*)(Vt + ch * 32 + ((quad ^ (ch & 3)) * 8));
                acco[nt] = __builtin_amdgcn_mfma_f32_16x16x32_bf16(ap, bv, acco[nt], 0, 0, 0);
            }
            __builtin_amdgcn_s_setprio(0);
        }

        // ONE barrier: vmcnt drain completes staging of buf^1; all reads of
        // buf[cur] done -> next iteration may stage into it.
        __syncthreads();
        cur ^= 1;
    }

    // ---- epilogue overlays on dead pool regions ----
    float* Ocomb  = (float*)pool;              // 3 x 32K at (grp-1)*32768
    float* relv_s = (float*)(pool + 98304);    // 4.5 KB (dead V region)
    float* pdiag4 = (float*)(pool + 104448);   // 4*64*9*4 = 9 KB (dead V region)

    // zero pdiag, stage relv, dump merge state (all regions disjoint)
    for (int e = tid; e < 2304; e += 1024) pdiag4[e] = 0.f;
    for (int e = tid; e < 1152; e += 1024) relv_s[e] = relv[e];
    if (grp != 0) {
        float* Oc = Ocomb + (grp - 1) * 8192;
        float* ms = mls[2 * (grp - 1)];
        float* ls = mls[2 * (grp - 1) + 1];
#pragma unroll
        for (int r4 = 0; r4 < 4; r4++) {
            const int row = row0 + quad * 4 + r4;
            if (c_ == 0) { ms[row] = m_run[r4]; ls[row] = l_run[r4]; }
#pragma unroll
            for (int nt = 0; nt < 8; nt++)
                Oc[row * 128 + nt * 16 + c_] = acco[nt][r4];
        }
    }
    __syncthreads();

    // dump register pdiag slots into zeroed table (disjoint (grp,row,dw))
#pragma unroll
    for (int r4 = 0; r4 < 4; r4++)
        if (pdw[r4] >= 0)
            pdiag4[(grp * 64 + row0 + quad * 4 + r4) * 9 + pdw[r4]] = pdacc[r4];
    __syncthreads();

    // ---- epilogue (group 0): 4-way combine, rel-v via pdiag, store ----
    if (grp == 0) {
#pragma unroll
        for (int r4 = 0; r4 < 4; r4++) {
            const int row = row0 + quad * 4 + r4;
            const int i = i0 + row;
            const float m0v = m_run[r4];
            const float m1v = mls[0][row], m2v = mls[2][row], m3v = mls[4][row];
            const float mn = fmaxf(fmaxf(m0v, m1v), fmaxf(m2v, m3v));
            const float a0 = __expf(m0v - mn);
            const float a1 = __expf(m1v - mn);
            const float a2 = __expf(m2v - mn);
            const float a3 = __expf(m3v - mn);
            const float l = l_run[r4] * a0 + mls[1][row] * a1 +
                            mls[3][row] * a2 + mls[5][row] * a3;
            const float invl = 1.f / l;
            float pd[9];
#pragma unroll
            for (int dd = 0; dd < 9; dd++) {
                const int j = i + dd - 4;
                pd[dd] = (j >= 0 && j < T_)
                    ? (pdiag4[(row) * 9 + dd] * a0 +
                       pdiag4[(64 + row) * 9 + dd] * a1 +
                       pdiag4[(128 + row) * 9 + dd] * a2 +
                       pdiag4[(192 + row) * 9 + dd] * a3) : 0.f;
            }
            ushort* ob = outp + ((size_t)(b * T_ + i) * H_ + h) * KC;
#pragma unroll
            for (int nt = 0; nt < 8; nt++) {
                const int col = nt * 16 + c_;
                float o = acco[nt][r4] * a0 +
                          Ocomb[row * 128 + col] * a1 +
                          Ocomb[8192 + row * 128 + col] * a2 +
                          Ocomb[16384 + row * 128 + col] * a3;
#pragma unroll
                for (int dd = 0; dd < 9; dd++) o += pd[dd] * relv_s[dd * 128 + col];
                ob[col] = f2b_rne(o * invl);
            }
        }
    }
}

// ---------------------------------------------------------------------------
extern "C" void kernel_launch(void* const* d_in, const int* in_sizes, int n_in,
                              void* d_out, int out_size, void* d_ws, size_t ws_size,
                              hipStream_t stream)
{
    const float* x    = (const float*)d_in[0];
    const float* c    = (const float*)d_in[1];
    const float* am   = (const float*)d_in[2];
    const float* Wq   = (const float*)d_in[3];
    const float* bq   = (const float*)d_in[4];
    const float* Wk   = (const float*)d_in[5];
    const float* bk   = (const float*)d_in[6];
    const float* Wv   = (const float*)d_in[7];
    const float* bv   = (const float*)d_in[8];
    const float* Wo   = (const float*)d_in[9];
    const float* bo   = (const float*)d_in[10];
    const float* relk = (const float*)d_in[11];
    const float* relv = (const float*)d_in[12];

    float* out = (float*)d_out;
    char* w8 = (char*)d_ws;
    ushort* qb  = (ushort*)(w8);
    ushort* kb  = (ushort*)(w8 + (4u << 20));
    ushort* vtb = (ushort*)(w8 + (8u << 20));   // [B,H,KC,T]
    ushort* ab  = (ushort*)(w8 + (12u << 20));
    ushort* xb  = (ushort*)(w8 + (16u << 20));
    ushort* cb  = (ushort*)(w8 + (20u << 20));
    ushort* Wqb = (ushort*)(w8 + (24u << 20));
    ushort* Wkb = Wqb + 262144;
    ushort* Wvb = Wkb + 262144;
    ushort* Wob = Wvb + 262144;

    cvt_all<<<2560, 256, 0, stream>>>(x, c, Wq, Wk, Wv, Wo, xb, cb, Wqb, Wkb, Wvb, Wob);

    gemm_qkv<<<dim3(256, 3), 256, 0, stream>>>(xb, cb, Wqb, Wkb, Wvb,
                                               bq, bk, bv, qb, kb, vtb);

    attn_mfma<<<256, 1024, 0, stream>>>(qb, kb, vtb, am, relk, relv, ab);

    gemm_o<<<dim3(256, 1), 256, 0, stream>>>(ab, Wob, bo, out);
}